// Round 8
// baseline (1898.300 us; speedup 1.0000x reference)
//
#include <hip/hip_runtime.h>

// ---------------------------------------------------------------------------
// Llama decoder layer, MI355X (gfx950).
// B=2 S=2048 HIDDEN=4096 HQ=32 HKV=8 D=128 INTER=11008, fp32 in/out.
// R8: GEMM block-order locality fix. Diagnosis: 739MB FETCH vs 124MB ideal
// (6x overfetch) -> aggregate demand 15.9TB/s vs 6.3 available -> MfmaUtil
// capped ~45%. Old mapping: each XCD sweeps all n per m-row (B re-streamed
// per row). New: column-major within XCD chunk -> B panel read by 16
// consecutive same-XCD blocks (L2-resident), A is L3-resident (33MB).
// Kernel body, schedule, templates: byte-identical to R7 (rule #19).
// ---------------------------------------------------------------------------

typedef __attribute__((ext_vector_type(8))) short bf16x8;
typedef __attribute__((ext_vector_type(4))) float f32x4;

__device__ __forceinline__ ushort f2bf(float f) {           // RNE fp32->bf16
  unsigned u = __float_as_uint(f);
  return (ushort)((u + 0x7fffu + ((u >> 16) & 1u)) >> 16);
}
__device__ __forceinline__ float bf2f(ushort u) {
  union { unsigned u32; float f; } x; x.u32 = ((unsigned)u) << 16; return x.f;
}
__device__ __forceinline__ void gload16(const void* g, void* l) {
  __builtin_amdgcn_global_load_lds((__attribute__((address_space(1))) void*)g,
                                   (__attribute__((address_space(3))) void*)l,
                                   16, 0, 0);
}

#define BARRIER() asm volatile("s_barrier" ::: "memory")
#define WAIT_LGKM0() asm volatile("s_waitcnt lgkmcnt(0)" ::: "memory")
#define WAIT_VM8() asm volatile("s_waitcnt vmcnt(8)" ::: "memory")
#define WAIT_VM4() asm volatile("s_waitcnt vmcnt(4)" ::: "memory")
#define WAIT_VM0() asm volatile("s_waitcnt vmcnt(0)" ::: "memory")

// --------------------------- RMSNorm (fp32 -> bf16) ------------------------
__global__ __launch_bounds__(256) void rmsnorm_kernel(
    const float* __restrict__ x, const float* __restrict__ g,
    ushort* __restrict__ out) {
  const int row = blockIdx.x, t = threadIdx.x;
  const float4* xp = (const float4*)(x + (size_t)row * 4096);
  float4 v[4]; float ss = 0.f;
#pragma unroll
  for (int i = 0; i < 4; ++i) {
    v[i] = xp[t + i * 256];
    ss += v[i].x * v[i].x + v[i].y * v[i].y + v[i].z * v[i].z + v[i].w * v[i].w;
  }
#pragma unroll
  for (int m = 32; m; m >>= 1) ss += __shfl_xor(ss, m);
  __shared__ float red[4];
  if ((t & 63) == 0) red[t >> 6] = ss;
  __syncthreads();
  float inv = rsqrtf((red[0] + red[1] + red[2] + red[3]) * (1.f / 4096.f) + 1e-6f);
  const float4* gp = (const float4*)g;
  ushort* op = out + (size_t)row * 4096;
#pragma unroll
  for (int i = 0; i < 4; ++i) {
    float4 gv = gp[t + i * 256];
    ushort4 o;
    o.x = f2bf(v[i].x * inv * gv.x); o.y = f2bf(v[i].y * inv * gv.y);
    o.z = f2bf(v[i].z * inv * gv.z); o.w = f2bf(v[i].w * inv * gv.w);
    *(ushort4*)(op + (size_t)(t + i * 256) * 4) = o;
  }
}

// ----------------- transpose + cast fp32 [R][ld_in] -> bf16 [C][R] ---------
__global__ __launch_bounds__(256) void transpose_cast_kernel(
    const float* __restrict__ in, ushort* __restrict__ out,
    int ld_in, int col_off, int R) {
  __shared__ ushort tile[64][65];
  const int t = threadIdx.x;
  const int r0 = blockIdx.x * 64, c0 = blockIdx.y * 64;
  const int rl = t >> 2, cl = (t & 3) * 16;
  const float* ip = in + (size_t)(r0 + rl) * ld_in + col_off + c0 + cl;
#pragma unroll
  for (int i = 0; i < 4; ++i) {
    float4 f = ((const float4*)ip)[i];
    tile[rl][cl + i * 4 + 0] = f2bf(f.x);
    tile[rl][cl + i * 4 + 1] = f2bf(f.y);
    tile[rl][cl + i * 4 + 2] = f2bf(f.z);
    tile[rl][cl + i * 4 + 3] = f2bf(f.w);
  }
  __syncthreads();
  union { ushort us[8]; uint4 v; } pk0, pk1;
#pragma unroll
  for (int j = 0; j < 8; ++j) pk0.us[j] = tile[cl + j][rl];
#pragma unroll
  for (int j = 0; j < 8; ++j) pk1.us[j] = tile[cl + 8 + j][rl];
  uint4* op = (uint4*)(out + (size_t)(c0 + rl) * R + r0 + cl);
  op[0] = pk0.v; op[1] = pk1.v;
}

// ------------------------- GEMM 256x256 8-phase ----------------------------
// R4 body; R8 changes ONLY the swz->(m0,n0) mapping (column-major in chunk).
template <typename OutT, bool RES>
__global__ __launch_bounds__(512, 2) void gemm256_kernel(
    const ushort* __restrict__ A, const ushort* __restrict__ Bt,
    OutT* __restrict__ C, const float* __restrict__ res,
    int M, int N, int K) {
  extern __shared__ ushort lds[];
  ushort* Al = lds;            // [buf:2][half:2][8192 ushorts]
  ushort* Bl = lds + 32768;
  const int t = threadIdx.x, l = t & 63, w = t >> 6;
  const int wr = w >> 2, wc = w & 3;
  const int lr = l & 15, lg = l >> 4;
  const int rhi = lr >> 3, rlo = lr & 7;
  const int srow = l >> 3, sg = (l & 7) ^ srow;

  const int nby = M >> 8;
  const int nwg = (N >> 8) * nby;
  const int cpx = nwg >> 3;
  const int bid = (int)blockIdx.x;
  const int swz = (bid & 7) * cpx + (bid >> 3);   // XCD chunk (nwg%8==0)
  const int m0 = (swz % nby) << 8;                // col-major: B panel shared
  const int n0 = (swz / nby) << 8;                // by 16 consecutive blocks

  const int lof0 = rhi * 512 + rlo * 64 + ((0 + lg) ^ rlo) * 8;  // kk=0
  const int lof1 = rhi * 512 + rlo * 64 + ((4 + lg) ^ rlo) * 8;  // kk=1

  const f32x4 fz = {0.f, 0.f, 0.f, 0.f};
  f32x4 acc[8][4];
#pragma unroll
  for (int i = 0; i < 8; ++i)
#pragma unroll
    for (int j = 0; j < 4; ++j) acc[i][j] = fz;
  bf16x8 a[8][2];
  bf16x8 bq[2][2];

  const ushort* Asrc = A + (size_t)(m0 + w * 8 + srow) * K + sg * 8;
  const ushort* Bsrc = Bt + (size_t)(n0 + w * 8 + srow) * K + sg * 8;
  const size_t rK64 = (size_t)64 * K, rK128 = (size_t)128 * K;
  ushort* Adst = Al + w * 512;
  ushort* Bdst = Bl + w * 512;

#define STAGE_A(buf, half, tile) do {                                   \
    const ushort* s_ = Asrc + (size_t)(half) * rK128 + ((tile) << 6);   \
    ushort* d_ = Adst + (buf) * 16384 + (half) * 8192;                  \
    gload16(s_, d_);                                                    \
    gload16(s_ + rK64, d_ + 4096);                                      \
  } while (0)
#define STAGE_B(buf, half, tile) do {                                   \
    const ushort* s_ = Bsrc + (size_t)(half) * rK128 + ((tile) << 6);   \
    ushort* d_ = Bdst + (buf) * 16384 + (half) * 8192;                  \
    gload16(s_, d_);                                                    \
    gload16(s_ + rK64, d_ + 4096);                                      \
  } while (0)
#define LDA4(AH, QM) do {                                                   \
    _Pragma("unroll") for (int mi_ = 0; mi_ < 4; ++mi_) {                   \
      a[(QM) * 4 + mi_][0] =                                                \
          *(const bf16x8*)((AH) + ((QM) * 4 + mi_) * 1024 + lof0);          \
      a[(QM) * 4 + mi_][1] =                                                \
          *(const bf16x8*)((AH) + ((QM) * 4 + mi_) * 1024 + lof1);          \
    } } while (0)
#define LDB2(BH, NQ) do {                                                   \
    _Pragma("unroll") for (int nj_ = 0; nj_ < 2; ++nj_) {                   \
      bq[nj_][0] = *(const bf16x8*)((BH) + ((NQ) * 2 + nj_) * 1024 + lof0); \
      bq[nj_][1] = *(const bf16x8*)((BH) + ((NQ) * 2 + nj_) * 1024 + lof1); \
    } } while (0)
#define MFMA16(QM, QN)                                                      \
    __builtin_amdgcn_s_setprio(1);                                          \
    _Pragma("unroll") for (int mi_ = 0; mi_ < 4; ++mi_)                     \
    _Pragma("unroll") for (int nj_ = 0; nj_ < 2; ++nj_) {                   \
      acc[(QM) * 4 + mi_][(QN) * 2 + nj_] =                                 \
          __builtin_amdgcn_mfma_f32_16x16x32_bf16(                          \
              a[(QM) * 4 + mi_][0], bq[nj_][0],                             \
              acc[(QM) * 4 + mi_][(QN) * 2 + nj_], 0, 0, 0);                \
      acc[(QM) * 4 + mi_][(QN) * 2 + nj_] =                                 \
          __builtin_amdgcn_mfma_f32_16x16x32_bf16(                          \
              a[(QM) * 4 + mi_][1], bq[nj_][1],                             \
              acc[(QM) * 4 + mi_][(QN) * 2 + nj_], 0, 0, 0);                \
    }                                                                       \
    __builtin_amdgcn_s_setprio(0);

  const ushort* A0h = Al + wr * 8192;
  const ushort* A1h = A0h + 16384;
  const ushort* B0h = Bl + (wc >> 1) * 8192 + (wc & 1) * 4096;
  const ushort* B1h = B0h + 16384;

  const int ntiles = K >> 6, nIter = K >> 7;
  // prologue: tile0 full -> buf0; tile1 A halves -> buf1
  STAGE_A(0, 0, 0); STAGE_A(0, 1, 0); STAGE_B(0, 0, 0); STAGE_B(0, 1, 0);
  STAGE_A(1, 0, 1); STAGE_A(1, 1, 1);
  WAIT_VM4(); BARRIER();

  for (int it = 0; it < nIter; ++it) {
    const int u = it * 2;
    // ---- tile u (buf0) ----
    LDA4(A0h, 0); LDB2(B0h, 0);                 // P1
    STAGE_B(1, 0, u + 1);
    BARRIER(); WAIT_LGKM0(); MFMA16(0, 0); BARRIER();
    LDA4(A0h, 1);                               // P2
    STAGE_B(1, 1, u + 1);
    BARRIER(); WAIT_LGKM0(); MFMA16(1, 0); BARRIER();
    LDB2(B0h, 1);                               // P3
    if (u + 2 < ntiles) STAGE_A(0, 0, u + 2);
    BARRIER(); WAIT_LGKM0(); MFMA16(0, 1); BARRIER();
    if (u + 2 < ntiles) STAGE_A(0, 1, u + 2);   // P4
    BARRIER(); MFMA16(1, 1);
    if (u + 2 < ntiles) { WAIT_VM4(); } else { WAIT_VM0(); }
    BARRIER();
    // ---- tile u+1 (buf1) ----
    LDA4(A1h, 0); LDB2(B1h, 0);                 // P5
    if (u + 2 < ntiles) STAGE_B(0, 0, u + 2);
    BARRIER(); WAIT_LGKM0(); MFMA16(0, 0); BARRIER();
    LDA4(A1h, 1);                               // P6
    if (u + 2 < ntiles) STAGE_B(0, 1, u + 2);
    BARRIER(); WAIT_LGKM0(); MFMA16(1, 0); BARRIER();
    LDB2(B1h, 1);                               // P7
    if (u + 3 < ntiles) STAGE_A(1, 0, u + 3);
    BARRIER(); WAIT_LGKM0(); MFMA16(0, 1); BARRIER();
    if (u + 3 < ntiles) STAGE_A(1, 1, u + 3);   // P8
    BARRIER(); MFMA16(1, 1);
    WAIT_VM4(); BARRIER();
  }

  // epilogue: C row = m0+wr*128+mi*16+lg*4+r, col = n0+wc*64+ni*16+lr
#pragma unroll
  for (int mi = 0; mi < 8; ++mi)
#pragma unroll
    for (int ni = 0; ni < 4; ++ni)
#pragma unroll
      for (int r = 0; r < 4; ++r) {
        int row = m0 + wr * 128 + mi * 16 + lg * 4 + r;
        int col = n0 + wc * 64 + ni * 16 + lr;
        size_t idx = (size_t)row * N + col;
        float v = acc[mi][ni][r];
        if (RES) v += res[idx];
        if constexpr (sizeof(OutT) == 2) C[idx] = f2bf(v);
        else                             C[idx] = v;
      }
#undef STAGE_A
#undef STAGE_B
#undef LDA4
#undef LDB2
#undef MFMA16
}

// ------------------------------ RoPE table ---------------------------------
__global__ void rope_table_kernel(const int* __restrict__ pos,
                                  float2* __restrict__ tab) {
  int idx = blockIdx.x * 256 + threadIdx.x;  // 2048*64
  int s = idx >> 6, fi = idx & 63;
  float inv = (float)exp(-(double)(2 * fi) / 128.0 * 9.210340371976184);
  float a = (float)pos[s] * inv;
  tab[idx] = make_float2(cosf(a), sinf(a));
}

// --------- RoPE + scatter qkv[T,6144] -> Qr[b,h,s,d] Kr[b,h,s,d] Vt[b,h,d,s]
__global__ __launch_bounds__(256) void rope_scatter_kernel(
    const ushort* __restrict__ qkv, const float2* __restrict__ tab,
    ushort* __restrict__ Qr, ushort* __restrict__ Kr, ushort* __restrict__ Vt) {
  __shared__ ushort vt[64][132];
  const int t = threadIdx.x, tt = blockIdx.x, h = blockIdx.y;  // h: 0..47
  const int row = t >> 2, c = (t & 3) * 16;
  const int tok = tt * 64 + row;
  const int b = tok >> 11, s = tok & 2047;
  const ushort* ip = qkv + (size_t)tok * 6144 + h * 128;
  union U { uint4 v; ushort us[8]; };
  U a0, a1, b0, b1;
  a0.v = *(const uint4*)(ip + c);      a1.v = *(const uint4*)(ip + c + 8);
  b0.v = *(const uint4*)(ip + c + 64); b1.v = *(const uint4*)(ip + c + 72);
  if (h < 40) {  // q or k head: NeoX rope on pairs (i, i+64)
    U o0, o1, o2, o3;
#pragma unroll
    for (int j = 0; j < 8; ++j) {
      float2 cs = tab[s * 64 + c + j];
      float x1 = bf2f(a0.us[j]), x2 = bf2f(b0.us[j]);
      o0.us[j] = f2bf(x1 * cs.x - x2 * cs.y);
      o2.us[j] = f2bf(x2 * cs.x + x1 * cs.y);
    }
#pragma unroll
    for (int j = 0; j < 8; ++j) {
      float2 cs = tab[s * 64 + c + 8 + j];
      float x1 = bf2f(a1.us[j]), x2 = bf2f(b1.us[j]);
      o1.us[j] = f2bf(x1 * cs.x - x2 * cs.y);
      o3.us[j] = f2bf(x2 * cs.x + x1 * cs.y);
    }
    ushort* base;
    if (h < 32) base = Qr + ((size_t)((b * 32 + h) * 2048 + s)) * 128;
    else        base = Kr + ((size_t)((b * 8 + (h - 32)) * 2048 + s)) * 128;
    *(uint4*)(base + c)      = o0.v; *(uint4*)(base + c + 8)  = o1.v;
    *(uint4*)(base + c + 64) = o2.v; *(uint4*)(base + c + 72) = o3.v;
  } else {  // v head: LDS transpose -> Vt[b,hv,d,s]
    const int hv = h - 40;
#pragma unroll
    for (int j = 0; j < 8; ++j) {
      vt[row][c + j]      = a0.us[j]; vt[row][c + 8 + j]  = a1.us[j];
      vt[row][c + 64 + j] = b0.us[j]; vt[row][c + 72 + j] = b1.us[j];
    }
    __syncthreads();
    const int d = t >> 1, s0 = (t & 1) * 32, sb = (tt & 31) * 64;
    U w0, w1, w2, w3;
#pragma unroll
    for (int j = 0; j < 8; ++j) {
      w0.us[j] = vt[s0 + j][d];      w1.us[j] = vt[s0 + 8 + j][d];
      w2.us[j] = vt[s0 + 16 + j][d]; w3.us[j] = vt[s0 + 24 + j][d];
    }
    ushort* vb = Vt + ((size_t)((b * 8 + hv) * 128 + d)) * 2048 + sb + s0;
    *(uint4*)(vb) = w0.v;      *(uint4*)(vb + 8) = w1.v;
    *(uint4*)(vb + 16) = w2.v; *(uint4*)(vb + 24) = w3.v;
  }
}

// --------------------------- flash attention -------------------------------
// 4 waves; wave owns 16 q rows x 64 kv cols. XOR-swizzled K/V/P LDS,
// K/V dbuf + counted vmcnt(8). Log2-domain softmax (scale*log2e folded into
// Q), row-sum via MFMA-of-ones, defer-max THR=8, diagonal-only mask.
__global__ __launch_bounds__(256) void attn_kernel(
    const ushort* __restrict__ Q, const ushort* __restrict__ K,
    const ushort* __restrict__ V, ushort* __restrict__ O) {
  extern __shared__ ushort sm[];
  ushort* Kl = sm;           // [2][64*128]
  ushort* Vl = sm + 16384;   // [2][128*64]
  ushort* Pl = sm + 32768;   // [64*64]
  const int t = threadIdx.x, l = t & 63, w = t >> 6;
  const int lr = l & 15, lg = l >> 4;
  const int qt = blockIdx.x, h = blockIdx.y, b = blockIdx.z;
  const int hkv = h >> 2;
  const f32x4 fzero = {0.f, 0.f, 0.f, 0.f};

  const int rm = lr & 7;
  int ksw[4], vsw[2];
#pragma unroll
  for (int ks = 0; ks < 4; ++ks) ksw[ks] = ((ks * 4 + lg) ^ rm) * 8;
  vsw[0] = (lg ^ rm) * 8;
  vsw[1] = ((4 + lg) ^ rm) * 8;
  const int kcol = ((t & 15) ^ ((t >> 4) & 7)) * 8;   // staging src swizzle
  const int vcol = ((t & 7) ^ ((t >> 3) & 7)) * 8;

  // Q fragment, pre-scaled by scale*log2e (log2-domain softmax)
  const float qscale = 0.08838834764831845f * 1.4426950408889634f;
  const ushort* qp =
      Q + ((size_t)((b * 32 + h) * 2048 + qt * 64 + w * 16 + lr)) * 128 + lg * 8;
  bf16x8 qf[4];
#pragma unroll
  for (int ks = 0; ks < 4; ++ks) {
    bf16x8 raw = *(const bf16x8*)(qp + ks * 32);
#pragma unroll
    for (int j = 0; j < 8; ++j)
      qf[ks][j] = (short)f2bf(bf2f((ushort)raw[j]) * qscale);
  }
  bf16x8 ones;
#pragma unroll
  for (int j = 0; j < 8; ++j) ones[j] = (short)0x3F80;
  WAIT_VM0();   // clean vmcnt ledger before staging pipeline

  const ushort* kg = K + ((size_t)(b * 8 + hkv)) * 2048 * 128;
  const ushort* vg = V + ((size_t)(b * 8 + hkv)) * 128 * 2048;

#define STAGE_KV(buf, s0_) do {                                              \
    _Pragma("unroll") for (int i_ = 0; i_ < 4; ++i_)                         \
      gload16(kg + (size_t)((s0_) + i_ * 16 + (t >> 4)) * 128 + kcol,        \
              (char*)Kl + (buf) * 16384 + i_ * 4096 + t * 16);               \
    _Pragma("unroll") for (int i_ = 0; i_ < 4; ++i_)                         \
      gload16(vg + (size_t)(i_ * 32 + (t >> 3)) * 2048 + (s0_) + vcol,       \
              (char*)Vl + (buf) * 16384 + i_ * 4096 + t * 16);               \
  } while (0)

  f32x4 accO[8];
#pragma unroll
  for (int i = 0; i < 8; ++i) accO[i] = fzero;
  float m_r[4] = {-1e30f, -1e30f, -1e30f, -1e30f};
  float l_r[4] = {0.f, 0.f, 0.f, 0.f};
  const int qrow = qt * 64 + w * 16 + lg * 4;

  STAGE_KV(0, 0);
  for (int j = 0; j <= qt; ++j) {
    if (j < qt) { STAGE_KV((j + 1) & 1, (j + 1) * 64); WAIT_VM8(); }
    else        { WAIT_VM0(); }
    BARRIER();
    const ushort* Kb = Kl + (j & 1) * 8192;
    const ushort* Vb = Vl + (j & 1) * 8192;

    f32x4 sc[4];
#pragma unroll
    for (int ni = 0; ni < 4; ++ni) sc[ni] = fzero;
    __builtin_amdgcn_s_setprio(1);
#pragma unroll
    for (int ni = 0; ni < 4; ++ni)
#pragma unroll
      for (int ks = 0; ks < 4; ++ks) {
        bf16x8 kf = *(const bf16x8*)(Kb + (ni * 16 + lr) * 128 + ksw[ks]);
        sc[ni] = __builtin_amdgcn_mfma_f32_16x16x32_bf16(qf[ks], kf, sc[ni], 0, 0, 0);
      }
    __builtin_amdgcn_s_setprio(0);
    if (j == qt) {   // causal mask on diagonal tile only
#pragma unroll
      for (int ni = 0; ni < 4; ++ni)
#pragma unroll
        for (int r = 0; r < 4; ++r)
          if (j * 64 + ni * 16 + lr > qrow + r) sc[ni][r] = -1e30f;
    }
    // per-row tile max (16-lane groups hold a row)
    float mx[4];
#pragma unroll
    for (int r = 0; r < 4; ++r) {
      float v = fmaxf(fmaxf(sc[0][r], sc[1][r]), fmaxf(sc[2][r], sc[3][r]));
#pragma unroll
      for (int m = 8; m; m >>= 1) v = fmaxf(v, __shfl_xor(v, m));
      mx[r] = v;
    }
    // defer-max: rescale only when a row's max grew by more than 8 (log2)
    bool ok = mx[0] <= m_r[0] + 8.f && mx[1] <= m_r[1] + 8.f &&
              mx[2] <= m_r[2] + 8.f && mx[3] <= m_r[3] + 8.f;
    if (!__all(ok)) {
#pragma unroll
      for (int r = 0; r < 4; ++r) {
        float mnew = fmaxf(m_r[r], mx[r]);
        float fsc = exp2f(m_r[r] - mnew);
        l_r[r] *= fsc;
        m_r[r] = mnew;
#pragma unroll
        for (int i = 0; i < 8; ++i) accO[i][r] *= fsc;
      }
    }
    // P = exp2(sc - m) -> LDS (swizzled write), same-wave rows only
#pragma unroll
    for (int ni = 0; ni < 4; ++ni)
#pragma unroll
      for (int r = 0; r < 4; ++r) {
        int prow = w * 16 + lg * 4 + r;
        int slot = (ni * 2 + (lr >> 3)) ^ (prow & 7);
        Pl[prow * 64 + slot * 8 + rm] = f2bf(exp2f(sc[ni][r] - m_r[r]));
      }
    WAIT_LGKM0();
    // PV + row-sum via MFMA-of-ones
    f32x4 accL = fzero;
    __builtin_amdgcn_s_setprio(1);
#pragma unroll
    for (int ks = 0; ks < 2; ++ks) {
      bf16x8 pf = *(const bf16x8*)(Pl + (w * 16 + lr) * 64 + vsw[ks]);
#pragma unroll
      for (int nf = 0; nf < 8; ++nf) {
        bf16x8 vf = *(const bf16x8*)(Vb + (nf * 16 + lr) * 64 + vsw[ks]);
        accO[nf] = __builtin_amdgcn_mfma_f32_16x16x32_bf16(pf, vf, accO[nf], 0, 0, 0);
      }
      accL = __builtin_amdgcn_mfma_f32_16x16x32_bf16(pf, ones, accL, 0, 0, 0);
    }
    __builtin_amdgcn_s_setprio(0);
#pragma unroll
    for (int r = 0; r < 4; ++r) l_r[r] += accL[r];
    BARRIER();
  }
#undef STAGE_KV
  float invl[4];
#pragma unroll
  for (int r = 0; r < 4; ++r) invl[r] = 1.f / l_r[r];
#pragma unroll
  for (int nf = 0; nf < 8; ++nf)
#pragma unroll
    for (int r = 0; r < 4; ++r) {
      int q = qt * 64 + w * 16 + lg * 4 + r;
      int d = nf * 16 + lr;
      O[((size_t)(b * 2048 + q)) * 4096 + h * 128 + d] = f2bf(accO[nf][r] * invl[r]);
    }
}

// ------------------------------- SwiGLU ------------------------------------
__global__ void swiglu_kernel(ushort* __restrict__ gate,
                              const ushort* __restrict__ up, int n8) {
  union U { uint4 v; ushort us[8]; };
  for (int i = blockIdx.x * blockDim.x + threadIdx.x; i < n8;
       i += gridDim.x * blockDim.x) {
    U gv, uv, ov;
    gv.v = ((const uint4*)gate)[i];
    uv.v = ((const uint4*)up)[i];
#pragma unroll
    for (int j = 0; j < 8; ++j) {
      float x = bf2f(gv.us[j]);
      float y = bf2f(uv.us[j]);
      ov.us[j] = f2bf(x / (1.f + __expf(-x)) * y);
    }
    ((uint4*)gate)[i] = ov.v;
  }
}

// ------------------------------ launcher -----------------------------------
#define OFF_W    ((size_t)0)
#define OFF_H1   ((size_t)90177536)
#define OFF_XN   ((size_t)157286400)
#define OFF_QKV  ((size_t)190840832)
#define OFF_TAB  ((size_t)241172480)
#define OFF_QR   ((size_t)242221056)
#define OFF_KR   ((size_t)275775488)
#define OFF_VT   ((size_t)284164096)
#define OFF_ATTN ((size_t)292552704)
#define OFF_GATE OFF_QKV
#define OFF_UP   ((size_t)326107136)
#define WS_NEED  ((size_t)416284672)

extern "C" void kernel_launch(void* const* d_in, const int* in_sizes, int n_in,
                              void* d_out, int out_size, void* d_ws,
                              size_t ws_size, hipStream_t stream) {
  (void)in_sizes; (void)n_in; (void)out_size;
  if (ws_size < WS_NEED) return;
  const float* hs     = (const float*)d_in[0];
  const int*   pos    = (const int*)d_in[1];
  const float* w_qkv  = (const float*)d_in[2];
  const float* w_o    = (const float*)d_in[3];
  const float* w_gu   = (const float*)d_in[4];
  const float* w_down = (const float*)d_in[5];
  const float* ln1    = (const float*)d_in[6];
  const float* ln2    = (const float*)d_in[7];
  float* out = (float*)d_out;
  char* ws = (char*)d_ws;

  ushort* W    = (ushort*)(ws + OFF_W);
  float*  h1   = (float*)(ws + OFF_H1);
  ushort* xn   = (ushort*)(ws + OFF_XN);
  ushort* qkv  = (ushort*)(ws + OFF_QKV);
  float2* tab  = (float2*)(ws + OFF_TAB);
  ushort* Qr   = (ushort*)(ws + OFF_QR);
  ushort* Kr   = (ushort*)(ws + OFF_KR);
  ushort* Vt   = (ushort*)(ws + OFF_VT);
  ushort* attn = (ushort*)(ws + OFF_ATTN);
  ushort* gate = (ushort*)(ws + OFF_GATE);
  ushort* up   = (ushort*)(ws + OFF_UP);

  auto kb = gemm256_kernel<ushort, false>;
  auto kf = gemm256_kernel<float, true>;
  hipFuncSetAttribute((const void*)kb, hipFuncAttributeMaxDynamicSharedMemorySize, 131072);
  hipFuncSetAttribute((const void*)kf, hipFuncAttributeMaxDynamicSharedMemorySize, 131072);
  hipFuncSetAttribute((const void*)attn_kernel, hipFuncAttributeMaxDynamicSharedMemorySize, 73728);

  // --- attention block ---
  rmsnorm_kernel<<<4096, 256, 0, stream>>>(hs, ln1, xn);
  transpose_cast_kernel<<<dim3(64, 96), 256, 0, stream>>>(w_qkv, W, 6144, 0, 4096);
  gemm256_kernel<ushort, false><<<384, 512, 131072, stream>>>(
      xn, W, qkv, nullptr, 4096, 6144, 4096);
  rope_table_kernel<<<512, 256, 0, stream>>>(pos, tab);
  rope_scatter_kernel<<<dim3(64, 48), 256, 0, stream>>>(qkv, tab, Qr, Kr, Vt);
  attn_kernel<<<dim3(32, 32, 2), 256, 73728, stream>>>(Qr, Kr, Vt, attn);
  transpose_cast_kernel<<<dim3(64, 64), 256, 0, stream>>>(w_o, W, 4096, 0, 4096);
  gemm256_kernel<float, true><<<256, 512, 131072, stream>>>(
      attn, W, h1, hs, 4096, 4096, 4096);

  // --- MLP block ---
  rmsnorm_kernel<<<4096, 256, 0, stream>>>(h1, ln2, xn);
  transpose_cast_kernel<<<dim3(64, 172), 256, 0, stream>>>(w_gu, W, 22016, 0, 4096);
  gemm256_kernel<ushort, false><<<688, 512, 131072, stream>>>(
      xn, W, gate, nullptr, 4096, 11008, 4096);
  transpose_cast_kernel<<<dim3(64, 172), 256, 0, stream>>>(w_gu, W, 22016, 11008, 4096);
  gemm256_kernel<ushort, false><<<688, 512, 131072, stream>>>(
      xn, W, up, nullptr, 4096, 11008, 4096);
  swiglu_kernel<<<2048, 256, 0, stream>>>(gate, up, (4096 * 11008) / 8);
  transpose_cast_kernel<<<dim3(172, 64), 256, 0, stream>>>(w_down, W, 4096, 0, 11008);
  gemm256_kernel<float, true><<<256, 512, 131072, stream>>>(
      gate, W, out, h1, 4096, 4096, 11008);
}

// Round 9
// 1810.511 us; speedup vs baseline: 1.0485x; 1.0485x over previous
//
#include <hip/hip_runtime.h>

// ---------------------------------------------------------------------------
// Llama decoder layer, MI355X (gfx950).
// B=2 S=2048 HIDDEN=4096 HQ=32 HKV=8 D=128 INTER=11008, fp32 in/out.
// R9: attn QBLK 64->128 (8 waves/block, KV traffic + barriers halved,
// LDS 80KB = 2 blocks/CU). GEMM byte-identical to R8 (LDS-serialization
// ceiling ~46% understood; not HBM-bound per R8 FETCH experiment).
// ---------------------------------------------------------------------------

typedef __attribute__((ext_vector_type(8))) short bf16x8;
typedef __attribute__((ext_vector_type(4))) float f32x4;

__device__ __forceinline__ ushort f2bf(float f) {           // RNE fp32->bf16
  unsigned u = __float_as_uint(f);
  return (ushort)((u + 0x7fffu + ((u >> 16) & 1u)) >> 16);
}
__device__ __forceinline__ float bf2f(ushort u) {
  union { unsigned u32; float f; } x; x.u32 = ((unsigned)u) << 16; return x.f;
}
__device__ __forceinline__ void gload16(const void* g, void* l) {
  __builtin_amdgcn_global_load_lds((__attribute__((address_space(1))) void*)g,
                                   (__attribute__((address_space(3))) void*)l,
                                   16, 0, 0);
}

#define BARRIER() asm volatile("s_barrier" ::: "memory")
#define WAIT_LGKM0() asm volatile("s_waitcnt lgkmcnt(0)" ::: "memory")
#define WAIT_VM4() asm volatile("s_waitcnt vmcnt(4)" ::: "memory")
#define WAIT_VM0() asm volatile("s_waitcnt vmcnt(0)" ::: "memory")

// --------------------------- RMSNorm (fp32 -> bf16) ------------------------
__global__ __launch_bounds__(256) void rmsnorm_kernel(
    const float* __restrict__ x, const float* __restrict__ g,
    ushort* __restrict__ out) {
  const int row = blockIdx.x, t = threadIdx.x;
  const float4* xp = (const float4*)(x + (size_t)row * 4096);
  float4 v[4]; float ss = 0.f;
#pragma unroll
  for (int i = 0; i < 4; ++i) {
    v[i] = xp[t + i * 256];
    ss += v[i].x * v[i].x + v[i].y * v[i].y + v[i].z * v[i].z + v[i].w * v[i].w;
  }
#pragma unroll
  for (int m = 32; m; m >>= 1) ss += __shfl_xor(ss, m);
  __shared__ float red[4];
  if ((t & 63) == 0) red[t >> 6] = ss;
  __syncthreads();
  float inv = rsqrtf((red[0] + red[1] + red[2] + red[3]) * (1.f / 4096.f) + 1e-6f);
  const float4* gp = (const float4*)g;
  ushort* op = out + (size_t)row * 4096;
#pragma unroll
  for (int i = 0; i < 4; ++i) {
    float4 gv = gp[t + i * 256];
    ushort4 o;
    o.x = f2bf(v[i].x * inv * gv.x); o.y = f2bf(v[i].y * inv * gv.y);
    o.z = f2bf(v[i].z * inv * gv.z); o.w = f2bf(v[i].w * inv * gv.w);
    *(ushort4*)(op + (size_t)(t + i * 256) * 4) = o;
  }
}

// ----------------- transpose + cast fp32 [R][ld_in] -> bf16 [C][R] ---------
__global__ __launch_bounds__(256) void transpose_cast_kernel(
    const float* __restrict__ in, ushort* __restrict__ out,
    int ld_in, int col_off, int R) {
  __shared__ ushort tile[64][65];
  const int t = threadIdx.x;
  const int r0 = blockIdx.x * 64, c0 = blockIdx.y * 64;
  const int rl = t >> 2, cl = (t & 3) * 16;
  const float* ip = in + (size_t)(r0 + rl) * ld_in + col_off + c0 + cl;
#pragma unroll
  for (int i = 0; i < 4; ++i) {
    float4 f = ((const float4*)ip)[i];
    tile[rl][cl + i * 4 + 0] = f2bf(f.x);
    tile[rl][cl + i * 4 + 1] = f2bf(f.y);
    tile[rl][cl + i * 4 + 2] = f2bf(f.z);
    tile[rl][cl + i * 4 + 3] = f2bf(f.w);
  }
  __syncthreads();
  union { ushort us[8]; uint4 v; } pk0, pk1;
#pragma unroll
  for (int j = 0; j < 8; ++j) pk0.us[j] = tile[cl + j][rl];
#pragma unroll
  for (int j = 0; j < 8; ++j) pk1.us[j] = tile[cl + 8 + j][rl];
  uint4* op = (uint4*)(out + (size_t)(c0 + rl) * R + r0 + cl);
  op[0] = pk0.v; op[1] = pk1.v;
}

// ------------------------- GEMM 256x256 8-phase ----------------------------
// Byte-identical to R8 (R4 body + col-major XCD chunk mapping).
template <typename OutT, bool RES>
__global__ __launch_bounds__(512, 2) void gemm256_kernel(
    const ushort* __restrict__ A, const ushort* __restrict__ Bt,
    OutT* __restrict__ C, const float* __restrict__ res,
    int M, int N, int K) {
  extern __shared__ ushort lds[];
  ushort* Al = lds;            // [buf:2][half:2][8192 ushorts]
  ushort* Bl = lds + 32768;
  const int t = threadIdx.x, l = t & 63, w = t >> 6;
  const int wr = w >> 2, wc = w & 3;
  const int lr = l & 15, lg = l >> 4;
  const int rhi = lr >> 3, rlo = lr & 7;
  const int srow = l >> 3, sg = (l & 7) ^ srow;

  const int nby = M >> 8;
  const int nwg = (N >> 8) * nby;
  const int cpx = nwg >> 3;
  const int bid = (int)blockIdx.x;
  const int swz = (bid & 7) * cpx + (bid >> 3);   // XCD chunk (nwg%8==0)
  const int m0 = (swz % nby) << 8;                // col-major: B panel shared
  const int n0 = (swz / nby) << 8;                // by 16 consecutive blocks

  const int lof0 = rhi * 512 + rlo * 64 + ((0 + lg) ^ rlo) * 8;  // kk=0
  const int lof1 = rhi * 512 + rlo * 64 + ((4 + lg) ^ rlo) * 8;  // kk=1

  const f32x4 fz = {0.f, 0.f, 0.f, 0.f};
  f32x4 acc[8][4];
#pragma unroll
  for (int i = 0; i < 8; ++i)
#pragma unroll
    for (int j = 0; j < 4; ++j) acc[i][j] = fz;
  bf16x8 a[8][2];
  bf16x8 bq[2][2];

  const ushort* Asrc = A + (size_t)(m0 + w * 8 + srow) * K + sg * 8;
  const ushort* Bsrc = Bt + (size_t)(n0 + w * 8 + srow) * K + sg * 8;
  const size_t rK64 = (size_t)64 * K, rK128 = (size_t)128 * K;
  ushort* Adst = Al + w * 512;
  ushort* Bdst = Bl + w * 512;

#define STAGE_A(buf, half, tile) do {                                   \
    const ushort* s_ = Asrc + (size_t)(half) * rK128 + ((tile) << 6);   \
    ushort* d_ = Adst + (buf) * 16384 + (half) * 8192;                  \
    gload16(s_, d_);                                                    \
    gload16(s_ + rK64, d_ + 4096);                                      \
  } while (0)
#define STAGE_B(buf, half, tile) do {                                   \
    const ushort* s_ = Bsrc + (size_t)(half) * rK128 + ((tile) << 6);   \
    ushort* d_ = Bdst + (buf) * 16384 + (half) * 8192;                  \
    gload16(s_, d_);                                                    \
    gload16(s_ + rK64, d_ + 4096);                                      \
  } while (0)
#define LDA4(AH, QM) do {                                                   \
    _Pragma("unroll") for (int mi_ = 0; mi_ < 4; ++mi_) {                   \
      a[(QM) * 4 + mi_][0] =                                                \
          *(const bf16x8*)((AH) + ((QM) * 4 + mi_) * 1024 + lof0);          \
      a[(QM) * 4 + mi_][1] =                                                \
          *(const bf16x8*)((AH) + ((QM) * 4 + mi_) * 1024 + lof1);          \
    } } while (0)
#define LDB2(BH, NQ) do {                                                   \
    _Pragma("unroll") for (int nj_ = 0; nj_ < 2; ++nj_) {                   \
      bq[nj_][0] = *(const bf16x8*)((BH) + ((NQ) * 2 + nj_) * 1024 + lof0); \
      bq[nj_][1] = *(const bf16x8*)((BH) + ((NQ) * 2 + nj_) * 1024 + lof1); \
    } } while (0)
#define MFMA16(QM, QN)                                                      \
    __builtin_amdgcn_s_setprio(1);                                          \
    _Pragma("unroll") for (int mi_ = 0; mi_ < 4; ++mi_)                     \
    _Pragma("unroll") for (int nj_ = 0; nj_ < 2; ++nj_) {                   \
      acc[(QM) * 4 + mi_][(QN) * 2 + nj_] =                                 \
          __builtin_amdgcn_mfma_f32_16x16x32_bf16(                          \
              a[(QM) * 4 + mi_][0], bq[nj_][0],                             \
              acc[(QM) * 4 + mi_][(QN) * 2 + nj_], 0, 0, 0);                \
      acc[(QM) * 4 + mi_][(QN) * 2 + nj_] =                                 \
          __builtin_amdgcn_mfma_f32_16x16x32_bf16(                          \
              a[(QM) * 4 + mi_][1], bq[nj_][1],                             \
              acc[(QM) * 4 + mi_][(QN) * 2 + nj_], 0, 0, 0);                \
    }                                                                       \
    __builtin_amdgcn_s_setprio(0);

  const ushort* A0h = Al + wr * 8192;
  const ushort* A1h = A0h + 16384;
  const ushort* B0h = Bl + (wc >> 1) * 8192 + (wc & 1) * 4096;
  const ushort* B1h = B0h + 16384;

  const int ntiles = K >> 6, nIter = K >> 7;
  // prologue: tile0 full -> buf0; tile1 A halves -> buf1
  STAGE_A(0, 0, 0); STAGE_A(0, 1, 0); STAGE_B(0, 0, 0); STAGE_B(0, 1, 0);
  STAGE_A(1, 0, 1); STAGE_A(1, 1, 1);
  WAIT_VM4(); BARRIER();

  for (int it = 0; it < nIter; ++it) {
    const int u = it * 2;
    // ---- tile u (buf0) ----
    LDA4(A0h, 0); LDB2(B0h, 0);                 // P1
    STAGE_B(1, 0, u + 1);
    BARRIER(); WAIT_LGKM0(); MFMA16(0, 0); BARRIER();
    LDA4(A0h, 1);                               // P2
    STAGE_B(1, 1, u + 1);
    BARRIER(); WAIT_LGKM0(); MFMA16(1, 0); BARRIER();
    LDB2(B0h, 1);                               // P3
    if (u + 2 < ntiles) STAGE_A(0, 0, u + 2);
    BARRIER(); WAIT_LGKM0(); MFMA16(0, 1); BARRIER();
    if (u + 2 < ntiles) STAGE_A(0, 1, u + 2);   // P4
    BARRIER(); MFMA16(1, 1);
    if (u + 2 < ntiles) { WAIT_VM4(); } else { WAIT_VM0(); }
    BARRIER();
    // ---- tile u+1 (buf1) ----
    LDA4(A1h, 0); LDB2(B1h, 0);                 // P5
    if (u + 2 < ntiles) STAGE_B(0, 0, u + 2);
    BARRIER(); WAIT_LGKM0(); MFMA16(0, 0); BARRIER();
    LDA4(A1h, 1);                               // P6
    if (u + 2 < ntiles) STAGE_B(0, 1, u + 2);
    BARRIER(); WAIT_LGKM0(); MFMA16(1, 0); BARRIER();
    LDB2(B1h, 1);                               // P7
    if (u + 3 < ntiles) STAGE_A(1, 0, u + 3);
    BARRIER(); WAIT_LGKM0(); MFMA16(0, 1); BARRIER();
    if (u + 3 < ntiles) STAGE_A(1, 1, u + 3);   // P8
    BARRIER(); MFMA16(1, 1);
    WAIT_VM4(); BARRIER();
  }

  // epilogue: C row = m0+wr*128+mi*16+lg*4+r, col = n0+wc*64+ni*16+lr
#pragma unroll
  for (int mi = 0; mi < 8; ++mi)
#pragma unroll
    for (int ni = 0; ni < 4; ++ni)
#pragma unroll
      for (int r = 0; r < 4; ++r) {
        int row = m0 + wr * 128 + mi * 16 + lg * 4 + r;
        int col = n0 + wc * 64 + ni * 16 + lr;
        size_t idx = (size_t)row * N + col;
        float v = acc[mi][ni][r];
        if (RES) v += res[idx];
        if constexpr (sizeof(OutT) == 2) C[idx] = f2bf(v);
        else                             C[idx] = v;
      }
#undef STAGE_A
#undef STAGE_B
#undef LDA4
#undef LDB2
#undef MFMA16
}

// ------------------------------ RoPE table ---------------------------------
__global__ void rope_table_kernel(const int* __restrict__ pos,
                                  float2* __restrict__ tab) {
  int idx = blockIdx.x * 256 + threadIdx.x;  // 2048*64
  int s = idx >> 6, fi = idx & 63;
  float inv = (float)exp(-(double)(2 * fi) / 128.0 * 9.210340371976184);
  float a = (float)pos[s] * inv;
  tab[idx] = make_float2(cosf(a), sinf(a));
}

// --------- RoPE + scatter qkv[T,6144] -> Qr[b,h,s,d] Kr[b,h,s,d] Vt[b,h,d,s]
__global__ __launch_bounds__(256) void rope_scatter_kernel(
    const ushort* __restrict__ qkv, const float2* __restrict__ tab,
    ushort* __restrict__ Qr, ushort* __restrict__ Kr, ushort* __restrict__ Vt) {
  __shared__ ushort vt[64][132];
  const int t = threadIdx.x, tt = blockIdx.x, h = blockIdx.y;  // h: 0..47
  const int row = t >> 2, c = (t & 3) * 16;
  const int tok = tt * 64 + row;
  const int b = tok >> 11, s = tok & 2047;
  const ushort* ip = qkv + (size_t)tok * 6144 + h * 128;
  union U { uint4 v; ushort us[8]; };
  U a0, a1, b0, b1;
  a0.v = *(const uint4*)(ip + c);      a1.v = *(const uint4*)(ip + c + 8);
  b0.v = *(const uint4*)(ip + c + 64); b1.v = *(const uint4*)(ip + c + 72);
  if (h < 40) {  // q or k head: NeoX rope on pairs (i, i+64)
    U o0, o1, o2, o3;
#pragma unroll
    for (int j = 0; j < 8; ++j) {
      float2 cs = tab[s * 64 + c + j];
      float x1 = bf2f(a0.us[j]), x2 = bf2f(b0.us[j]);
      o0.us[j] = f2bf(x1 * cs.x - x2 * cs.y);
      o2.us[j] = f2bf(x2 * cs.x + x1 * cs.y);
    }
#pragma unroll
    for (int j = 0; j < 8; ++j) {
      float2 cs = tab[s * 64 + c + 8 + j];
      float x1 = bf2f(a1.us[j]), x2 = bf2f(b1.us[j]);
      o1.us[j] = f2bf(x1 * cs.x - x2 * cs.y);
      o3.us[j] = f2bf(x2 * cs.x + x1 * cs.y);
    }
    ushort* base;
    if (h < 32) base = Qr + ((size_t)((b * 32 + h) * 2048 + s)) * 128;
    else        base = Kr + ((size_t)((b * 8 + (h - 32)) * 2048 + s)) * 128;
    *(uint4*)(base + c)      = o0.v; *(uint4*)(base + c + 8)  = o1.v;
    *(uint4*)(base + c + 64) = o2.v; *(uint4*)(base + c + 72) = o3.v;
  } else {  // v head: LDS transpose -> Vt[b,hv,d,s]
    const int hv = h - 40;
#pragma unroll
    for (int j = 0; j < 8; ++j) {
      vt[row][c + j]      = a0.us[j]; vt[row][c + 8 + j]  = a1.us[j];
      vt[row][c + 64 + j] = b0.us[j]; vt[row][c + 72 + j] = b1.us[j];
    }
    __syncthreads();
    const int d = t >> 1, s0 = (t & 1) * 32, sb = (tt & 31) * 64;
    U w0, w1, w2, w3;
#pragma unroll
    for (int j = 0; j < 8; ++j) {
      w0.us[j] = vt[s0 + j][d];      w1.us[j] = vt[s0 + 8 + j][d];
      w2.us[j] = vt[s0 + 16 + j][d]; w3.us[j] = vt[s0 + 24 + j][d];
    }
    ushort* vb = Vt + ((size_t)((b * 8 + hv) * 128 + d)) * 2048 + sb + s0;
    *(uint4*)(vb) = w0.v;      *(uint4*)(vb + 8) = w1.v;
    *(uint4*)(vb + 16) = w2.v; *(uint4*)(vb + 24) = w3.v;
  }
}

// --------------------------- flash attention -------------------------------
// R9: QBLK=128, 8 waves (wave w owns rows w*16..w*16+15), KVBLK=64.
// XOR-swizzled K/V/P LDS, K/V dbuf + counted vmcnt(4) (4 loads/thread/tile).
// Log2-domain softmax, row-sum via MFMA-of-ones, defer-max THR=8,
// wave-uniform mask branch. LDS 80KB -> 2 blocks/CU.
__global__ __launch_bounds__(512) void attn_kernel(
    const ushort* __restrict__ Q, const ushort* __restrict__ K,
    const ushort* __restrict__ V, ushort* __restrict__ O) {
  extern __shared__ ushort sm[];
  ushort* Kl = sm;           // [2][64 s][128 d]
  ushort* Vl = sm + 16384;   // [2][128 d][64 s]
  ushort* Pl = sm + 32768;   // [128][64]
  const int t = threadIdx.x, l = t & 63, w = t >> 6;   // w: 0..7
  const int lr = l & 15, lg = l >> 4;
  const int qb = blockIdx.x, h = blockIdx.y, b = blockIdx.z;
  const int hkv = h >> 2;
  const f32x4 fzero = {0.f, 0.f, 0.f, 0.f};

  const int rm = lr & 7;
  int ksw[4], vsw[2];
#pragma unroll
  for (int ks = 0; ks < 4; ++ks) ksw[ks] = ((ks * 4 + lg) ^ rm) * 8;
  vsw[0] = (lg ^ rm) * 8;
  vsw[1] = ((4 + lg) ^ rm) * 8;
  const int kcol = ((t & 15) ^ ((t >> 4) & 7)) * 8;   // staging src swizzle
  const int vcol = ((t & 7) ^ ((t >> 3) & 7)) * 8;

  // Q fragment, pre-scaled by scale*log2e (log2-domain softmax)
  const float qscale = 0.08838834764831845f * 1.4426950408889634f;
  const ushort* qp =
      Q + ((size_t)((b * 32 + h) * 2048 + qb * 128 + w * 16 + lr)) * 128 + lg * 8;
  bf16x8 qf[4];
#pragma unroll
  for (int ks = 0; ks < 4; ++ks) {
    bf16x8 raw = *(const bf16x8*)(qp + ks * 32);
#pragma unroll
    for (int j = 0; j < 8; ++j)
      qf[ks][j] = (short)f2bf(bf2f((ushort)raw[j]) * qscale);
  }
  bf16x8 ones;
#pragma unroll
  for (int j = 0; j < 8; ++j) ones[j] = (short)0x3F80;
  WAIT_VM0();   // clean vmcnt ledger before staging pipeline

  const ushort* kg = K + ((size_t)(b * 8 + hkv)) * 2048 * 128;
  const ushort* vg = V + ((size_t)(b * 8 + hkv)) * 128 * 2048;

  // 512 threads stage one 64x128 K tile (2 loads) + one 128x64 V tile (2).
#define STAGE_KV(buf, s0_) do {                                              \
    _Pragma("unroll") for (int i_ = 0; i_ < 2; ++i_)                         \
      gload16(kg + (size_t)((s0_) + i_ * 32 + (t >> 4)) * 128 + kcol,        \
              (char*)Kl + (buf) * 16384 + i_ * 8192 + t * 16);               \
    _Pragma("unroll") for (int i_ = 0; i_ < 2; ++i_)                         \
      gload16(vg + (size_t)(i_ * 64 + (t >> 3)) * 2048 + (s0_) + vcol,       \
              (char*)Vl + (buf) * 16384 + i_ * 8192 + t * 16);               \
  } while (0)

  f32x4 accO[8];
#pragma unroll
  for (int i = 0; i < 8; ++i) accO[i] = fzero;
  float m_r[4] = {-1e30f, -1e30f, -1e30f, -1e30f};
  float l_r[4] = {0.f, 0.f, 0.f, 0.f};
  const int qrow = qb * 128 + w * 16 + lg * 4;
  const int wrow0 = qb * 128 + w * 16;         // wave's min q-row
  const int jend = 2 * qb + 1;

  STAGE_KV(0, 0);
  for (int j = 0; j <= jend; ++j) {
    if (j < jend) { STAGE_KV((j + 1) & 1, (j + 1) * 64); WAIT_VM4(); }
    else          { WAIT_VM0(); }
    BARRIER();
    const ushort* Kb = Kl + (j & 1) * 8192;
    const ushort* Vb = Vl + (j & 1) * 8192;

    f32x4 sc[4];
#pragma unroll
    for (int ni = 0; ni < 4; ++ni) sc[ni] = fzero;
    __builtin_amdgcn_s_setprio(1);
#pragma unroll
    for (int ni = 0; ni < 4; ++ni)
#pragma unroll
      for (int ks = 0; ks < 4; ++ks) {
        bf16x8 kf = *(const bf16x8*)(Kb + (ni * 16 + lr) * 128 + ksw[ks]);
        sc[ni] = __builtin_amdgcn_mfma_f32_16x16x32_bf16(qf[ks], kf, sc[ni], 0, 0, 0);
      }
    __builtin_amdgcn_s_setprio(0);
    if (j * 64 + 63 > wrow0) {   // wave-uniform: tile crosses this wave's rows
#pragma unroll
      for (int ni = 0; ni < 4; ++ni)
#pragma unroll
        for (int r = 0; r < 4; ++r)
          if (j * 64 + ni * 16 + lr > qrow + r) sc[ni][r] = -1e30f;
    }
    // per-row tile max (16-lane groups hold a row)
    float mx[4];
#pragma unroll
    for (int r = 0; r < 4; ++r) {
      float v = fmaxf(fmaxf(sc[0][r], sc[1][r]), fmaxf(sc[2][r], sc[3][r]));
#pragma unroll
      for (int m = 8; m; m >>= 1) v = fmaxf(v, __shfl_xor(v, m));
      mx[r] = v;
    }
    // defer-max: rescale only when a row's max grew by more than 8 (log2)
    bool ok = mx[0] <= m_r[0] + 8.f && mx[1] <= m_r[1] + 8.f &&
              mx[2] <= m_r[2] + 8.f && mx[3] <= m_r[3] + 8.f;
    if (!__all(ok)) {
#pragma unroll
      for (int r = 0; r < 4; ++r) {
        float mnew = fmaxf(m_r[r], mx[r]);
        float fsc = exp2f(m_r[r] - mnew);
        l_r[r] *= fsc;
        m_r[r] = mnew;
#pragma unroll
        for (int i = 0; i < 8; ++i) accO[i][r] *= fsc;
      }
    }
    // P = exp2(sc - m) -> LDS (swizzled write), same-wave rows only
#pragma unroll
    for (int ni = 0; ni < 4; ++ni)
#pragma unroll
      for (int r = 0; r < 4; ++r) {
        int prow = w * 16 + lg * 4 + r;
        int slot = (ni * 2 + (lr >> 3)) ^ (prow & 7);
        Pl[prow * 64 + slot * 8 + rm] = f2bf(exp2f(sc[ni][r] - m_r[r]));
      }
    WAIT_LGKM0();
    // PV + row-sum via MFMA-of-ones
    f32x4 accL = fzero;
    __builtin_amdgcn_s_setprio(1);
#pragma unroll
    for (int ks = 0; ks < 2; ++ks) {
      bf16x8 pf = *(const bf16x8*)(Pl + (w * 16 + lr) * 64 + vsw[ks]);
#pragma unroll
      for (int nf = 0; nf < 8; ++nf) {
        bf16x8 vf = *(const bf16x8*)(Vb + (nf * 16 + lr) * 64 + vsw[ks]);
        accO[nf] = __builtin_amdgcn_mfma_f32_16x16x32_bf16(pf, vf, accO[nf], 0, 0, 0);
      }
      accL = __builtin_amdgcn_mfma_f32_16x16x32_bf16(pf, ones, accL, 0, 0, 0);
    }
    __builtin_amdgcn_s_setprio(0);
#pragma unroll
    for (int r = 0; r < 4; ++r) l_r[r] += accL[r];
    BARRIER();
  }
#undef STAGE_KV
  float invl[4];
#pragma unroll
  for (int r = 0; r < 4; ++r) invl[r] = 1.f / l_r[r];
#pragma unroll
  for (int nf = 0; nf < 8; ++nf)
#pragma unroll
    for (int r = 0; r < 4; ++r) {
      int q = qb * 128 + w * 16 + lg * 4 + r;
      int d = nf * 16 + lr;
      O[((size_t)(b * 2048 + q)) * 4096 + h * 128 + d] = f2bf(accO[nf][r] * invl[r]);
    }
}

// ------------------------------- SwiGLU ------------------------------------
__global__ void swiglu_kernel(ushort* __restrict__ gate,
                              const ushort* __restrict__ up, int n8) {
  union U { uint4 v; ushort us[8]; };
  for (int i = blockIdx.x * blockDim.x + threadIdx.x; i < n8;
       i += gridDim.x * blockDim.x) {
    U gv, uv, ov;
    gv.v = ((const uint4*)gate)[i];
    uv.v = ((const uint4*)up)[i];
#pragma unroll
    for (int j = 0; j < 8; ++j) {
      float x = bf2f(gv.us[j]);
      float y = bf2f(uv.us[j]);
      ov.us[j] = f2bf(x / (1.f + __expf(-x)) * y);
    }
    ((uint4*)gate)[i] = ov.v;
  }
}

// ------------------------------ launcher -----------------------------------
#define OFF_W    ((size_t)0)
#define OFF_H1   ((size_t)90177536)
#define OFF_XN   ((size_t)157286400)
#define OFF_QKV  ((size_t)190840832)
#define OFF_TAB  ((size_t)241172480)
#define OFF_QR   ((size_t)242221056)
#define OFF_KR   ((size_t)275775488)
#define OFF_VT   ((size_t)284164096)
#define OFF_ATTN ((size_t)292552704)
#define OFF_GATE OFF_QKV
#define OFF_UP   ((size_t)326107136)
#define WS_NEED  ((size_t)416284672)

extern "C" void kernel_launch(void* const* d_in, const int* in_sizes, int n_in,
                              void* d_out, int out_size, void* d_ws,
                              size_t ws_size, hipStream_t stream) {
  (void)in_sizes; (void)n_in; (void)out_size;
  if (ws_size < WS_NEED) return;
  const float* hs     = (const float*)d_in[0];
  const int*   pos    = (const int*)d_in[1];
  const float* w_qkv  = (const float*)d_in[2];
  const float* w_o    = (const float*)d_in[3];
  const float* w_gu   = (const float*)d_in[4];
  const float* w_down = (const float*)d_in[5];
  const float* ln1    = (const float*)d_in[6];
  const float* ln2    = (const float*)d_in[7];
  float* out = (float*)d_out;
  char* ws = (char*)d_ws;

  ushort* W    = (ushort*)(ws + OFF_W);
  float*  h1   = (float*)(ws + OFF_H1);
  ushort* xn   = (ushort*)(ws + OFF_XN);
  ushort* qkv  = (ushort*)(ws + OFF_QKV);
  float2* tab  = (float2*)(ws + OFF_TAB);
  ushort* Qr   = (ushort*)(ws + OFF_QR);
  ushort* Kr   = (ushort*)(ws + OFF_KR);
  ushort* Vt   = (ushort*)(ws + OFF_VT);
  ushort* attn = (ushort*)(ws + OFF_ATTN);
  ushort* gate = (ushort*)(ws + OFF_GATE);
  ushort* up   = (ushort*)(ws + OFF_UP);

  auto kb = gemm256_kernel<ushort, false>;
  auto kf = gemm256_kernel<float, true>;
  hipFuncSetAttribute((const void*)kb, hipFuncAttributeMaxDynamicSharedMemorySize, 131072);
  hipFuncSetAttribute((const void*)kf, hipFuncAttributeMaxDynamicSharedMemorySize, 131072);
  hipFuncSetAttribute((const void*)attn_kernel, hipFuncAttributeMaxDynamicSharedMemorySize, 81920);

  // --- attention block ---
  rmsnorm_kernel<<<4096, 256, 0, stream>>>(hs, ln1, xn);
  transpose_cast_kernel<<<dim3(64, 96), 256, 0, stream>>>(w_qkv, W, 6144, 0, 4096);
  gemm256_kernel<ushort, false><<<384, 512, 131072, stream>>>(
      xn, W, qkv, nullptr, 4096, 6144, 4096);
  rope_table_kernel<<<512, 256, 0, stream>>>(pos, tab);
  rope_scatter_kernel<<<dim3(64, 48), 256, 0, stream>>>(qkv, tab, Qr, Kr, Vt);
  attn_kernel<<<dim3(16, 32, 2), 512, 81920, stream>>>(Qr, Kr, Vt, attn);
  transpose_cast_kernel<<<dim3(64, 64), 256, 0, stream>>>(w_o, W, 4096, 0, 4096);
  gemm256_kernel<float, true><<<256, 512, 131072, stream>>>(
      attn, W, h1, hs, 4096, 4096, 4096);

  // --- MLP block ---
  rmsnorm_kernel<<<4096, 256, 0, stream>>>(h1, ln2, xn);
  transpose_cast_kernel<<<dim3(64, 172), 256, 0, stream>>>(w_gu, W, 22016, 0, 4096);
  gemm256_kernel<ushort, false><<<688, 512, 131072, stream>>>(
      xn, W, gate, nullptr, 4096, 11008, 4096);
  transpose_cast_kernel<<<dim3(64, 172), 256, 0, stream>>>(w_gu, W, 22016, 11008, 4096);
  gemm256_kernel<ushort, false><<<688, 512, 131072, stream>>>(
      xn, W, up, nullptr, 4096, 11008, 4096);
  swiglu_kernel<<<2048, 256, 0, stream>>>(gate, up, (4096 * 11008) / 8);
  transpose_cast_kernel<<<dim3(172, 64), 256, 0, stream>>>(w_down, W, 4096, 0, 11008);
  gemm256_kernel<float, true><<<256, 512, 131072, stream>>>(
      gate, W, out, h1, 4096, 4096, 11008);
}

// Round 10
// 1794.078 us; speedup vs baseline: 1.0581x; 1.0092x over previous
//
#include <hip/hip_runtime.h>

// ---------------------------------------------------------------------------
// Llama decoder layer, MI355X (gfx950).
// B=2 S=2048 HIDDEN=4096 HQ=32 HKV=8 D=128 INTER=11008, fp32 in/out.
// R10: SwiGLU fused into up-GEMM epilogue via a SEPARATE copy-pasted kernel
// (gemm256_swiglu_kernel) so the two proven gemm256_kernel instantiations
// stay byte-identical (rule #19: R5's template-param refactor regressed).
// Removes the 270MB swiglu pass. GEMM/attn otherwise frozen at R9 state.
// ---------------------------------------------------------------------------

typedef __attribute__((ext_vector_type(8))) short bf16x8;
typedef __attribute__((ext_vector_type(4))) float f32x4;

__device__ __forceinline__ ushort f2bf(float f) {           // RNE fp32->bf16
  unsigned u = __float_as_uint(f);
  return (ushort)((u + 0x7fffu + ((u >> 16) & 1u)) >> 16);
}
__device__ __forceinline__ float bf2f(ushort u) {
  union { unsigned u32; float f; } x; x.u32 = ((unsigned)u) << 16; return x.f;
}
__device__ __forceinline__ void gload16(const void* g, void* l) {
  __builtin_amdgcn_global_load_lds((__attribute__((address_space(1))) void*)g,
                                   (__attribute__((address_space(3))) void*)l,
                                   16, 0, 0);
}

#define BARRIER() asm volatile("s_barrier" ::: "memory")
#define WAIT_LGKM0() asm volatile("s_waitcnt lgkmcnt(0)" ::: "memory")
#define WAIT_VM4() asm volatile("s_waitcnt vmcnt(4)" ::: "memory")
#define WAIT_VM0() asm volatile("s_waitcnt vmcnt(0)" ::: "memory")

// --------------------------- RMSNorm (fp32 -> bf16) ------------------------
__global__ __launch_bounds__(256) void rmsnorm_kernel(
    const float* __restrict__ x, const float* __restrict__ g,
    ushort* __restrict__ out) {
  const int row = blockIdx.x, t = threadIdx.x;
  const float4* xp = (const float4*)(x + (size_t)row * 4096);
  float4 v[4]; float ss = 0.f;
#pragma unroll
  for (int i = 0; i < 4; ++i) {
    v[i] = xp[t + i * 256];
    ss += v[i].x * v[i].x + v[i].y * v[i].y + v[i].z * v[i].z + v[i].w * v[i].w;
  }
#pragma unroll
  for (int m = 32; m; m >>= 1) ss += __shfl_xor(ss, m);
  __shared__ float red[4];
  if ((t & 63) == 0) red[t >> 6] = ss;
  __syncthreads();
  float inv = rsqrtf((red[0] + red[1] + red[2] + red[3]) * (1.f / 4096.f) + 1e-6f);
  const float4* gp = (const float4*)g;
  ushort* op = out + (size_t)row * 4096;
#pragma unroll
  for (int i = 0; i < 4; ++i) {
    float4 gv = gp[t + i * 256];
    ushort4 o;
    o.x = f2bf(v[i].x * inv * gv.x); o.y = f2bf(v[i].y * inv * gv.y);
    o.z = f2bf(v[i].z * inv * gv.z); o.w = f2bf(v[i].w * inv * gv.w);
    *(ushort4*)(op + (size_t)(t + i * 256) * 4) = o;
  }
}

// ----------------- transpose + cast fp32 [R][ld_in] -> bf16 [C][R] ---------
__global__ __launch_bounds__(256) void transpose_cast_kernel(
    const float* __restrict__ in, ushort* __restrict__ out,
    int ld_in, int col_off, int R) {
  __shared__ ushort tile[64][65];
  const int t = threadIdx.x;
  const int r0 = blockIdx.x * 64, c0 = blockIdx.y * 64;
  const int rl = t >> 2, cl = (t & 3) * 16;
  const float* ip = in + (size_t)(r0 + rl) * ld_in + col_off + c0 + cl;
#pragma unroll
  for (int i = 0; i < 4; ++i) {
    float4 f = ((const float4*)ip)[i];
    tile[rl][cl + i * 4 + 0] = f2bf(f.x);
    tile[rl][cl + i * 4 + 1] = f2bf(f.y);
    tile[rl][cl + i * 4 + 2] = f2bf(f.z);
    tile[rl][cl + i * 4 + 3] = f2bf(f.w);
  }
  __syncthreads();
  union { ushort us[8]; uint4 v; } pk0, pk1;
#pragma unroll
  for (int j = 0; j < 8; ++j) pk0.us[j] = tile[cl + j][rl];
#pragma unroll
  for (int j = 0; j < 8; ++j) pk1.us[j] = tile[cl + 8 + j][rl];
  uint4* op = (uint4*)(out + (size_t)(c0 + rl) * R + r0 + cl);
  op[0] = pk0.v; op[1] = pk1.v;
}

// ------------------------- GEMM 256x256 8-phase ----------------------------
// Byte-identical to R8/R9 (R4 body + col-major XCD chunk mapping).
template <typename OutT, bool RES>
__global__ __launch_bounds__(512, 2) void gemm256_kernel(
    const ushort* __restrict__ A, const ushort* __restrict__ Bt,
    OutT* __restrict__ C, const float* __restrict__ res,
    int M, int N, int K) {
  extern __shared__ ushort lds[];
  ushort* Al = lds;            // [buf:2][half:2][8192 ushorts]
  ushort* Bl = lds + 32768;
  const int t = threadIdx.x, l = t & 63, w = t >> 6;
  const int wr = w >> 2, wc = w & 3;
  const int lr = l & 15, lg = l >> 4;
  const int rhi = lr >> 3, rlo = lr & 7;
  const int srow = l >> 3, sg = (l & 7) ^ srow;

  const int nby = M >> 8;
  const int nwg = (N >> 8) * nby;
  const int cpx = nwg >> 3;
  const int bid = (int)blockIdx.x;
  const int swz = (bid & 7) * cpx + (bid >> 3);   // XCD chunk (nwg%8==0)
  const int m0 = (swz % nby) << 8;                // col-major: B panel shared
  const int n0 = (swz / nby) << 8;                // by 16 consecutive blocks

  const int lof0 = rhi * 512 + rlo * 64 + ((0 + lg) ^ rlo) * 8;  // kk=0
  const int lof1 = rhi * 512 + rlo * 64 + ((4 + lg) ^ rlo) * 8;  // kk=1

  const f32x4 fz = {0.f, 0.f, 0.f, 0.f};
  f32x4 acc[8][4];
#pragma unroll
  for (int i = 0; i < 8; ++i)
#pragma unroll
    for (int j = 0; j < 4; ++j) acc[i][j] = fz;
  bf16x8 a[8][2];
  bf16x8 bq[2][2];

  const ushort* Asrc = A + (size_t)(m0 + w * 8 + srow) * K + sg * 8;
  const ushort* Bsrc = Bt + (size_t)(n0 + w * 8 + srow) * K + sg * 8;
  const size_t rK64 = (size_t)64 * K, rK128 = (size_t)128 * K;
  ushort* Adst = Al + w * 512;
  ushort* Bdst = Bl + w * 512;

#define STAGE_A(buf, half, tile) do {                                   \
    const ushort* s_ = Asrc + (size_t)(half) * rK128 + ((tile) << 6);   \
    ushort* d_ = Adst + (buf) * 16384 + (half) * 8192;                  \
    gload16(s_, d_);                                                    \
    gload16(s_ + rK64, d_ + 4096);                                      \
  } while (0)
#define STAGE_B(buf, half, tile) do {                                   \
    const ushort* s_ = Bsrc + (size_t)(half) * rK128 + ((tile) << 6);   \
    ushort* d_ = Bdst + (buf) * 16384 + (half) * 8192;                  \
    gload16(s_, d_);                                                    \
    gload16(s_ + rK64, d_ + 4096);                                      \
  } while (0)
#define LDA4(AH, QM) do {                                                   \
    _Pragma("unroll") for (int mi_ = 0; mi_ < 4; ++mi_) {                   \
      a[(QM) * 4 + mi_][0] =                                                \
          *(const bf16x8*)((AH) + ((QM) * 4 + mi_) * 1024 + lof0);          \
      a[(QM) * 4 + mi_][1] =                                                \
          *(const bf16x8*)((AH) + ((QM) * 4 + mi_) * 1024 + lof1);          \
    } } while (0)
#define LDB2(BH, NQ) do {                                                   \
    _Pragma("unroll") for (int nj_ = 0; nj_ < 2; ++nj_) {                   \
      bq[nj_][0] = *(const bf16x8*)((BH) + ((NQ) * 2 + nj_) * 1024 + lof0); \
      bq[nj_][1] = *(const bf16x8*)((BH) + ((NQ) * 2 + nj_) * 1024 + lof1); \
    } } while (0)
#define MFMA16(QM, QN)                                                      \
    __builtin_amdgcn_s_setprio(1);                                          \
    _Pragma("unroll") for (int mi_ = 0; mi_ < 4; ++mi_)                     \
    _Pragma("unroll") for (int nj_ = 0; nj_ < 2; ++nj_) {                   \
      acc[(QM) * 4 + mi_][(QN) * 2 + nj_] =                                 \
          __builtin_amdgcn_mfma_f32_16x16x32_bf16(                          \
              a[(QM) * 4 + mi_][0], bq[nj_][0],                             \
              acc[(QM) * 4 + mi_][(QN) * 2 + nj_], 0, 0, 0);                \
      acc[(QM) * 4 + mi_][(QN) * 2 + nj_] =                                 \
          __builtin_amdgcn_mfma_f32_16x16x32_bf16(                          \
              a[(QM) * 4 + mi_][1], bq[nj_][1],                             \
              acc[(QM) * 4 + mi_][(QN) * 2 + nj_], 0, 0, 0);                \
    }                                                                       \
    __builtin_amdgcn_s_setprio(0);

  const ushort* A0h = Al + wr * 8192;
  const ushort* A1h = A0h + 16384;
  const ushort* B0h = Bl + (wc >> 1) * 8192 + (wc & 1) * 4096;
  const ushort* B1h = B0h + 16384;

  const int ntiles = K >> 6, nIter = K >> 7;
  // prologue: tile0 full -> buf0; tile1 A halves -> buf1
  STAGE_A(0, 0, 0); STAGE_A(0, 1, 0); STAGE_B(0, 0, 0); STAGE_B(0, 1, 0);
  STAGE_A(1, 0, 1); STAGE_A(1, 1, 1);
  WAIT_VM4(); BARRIER();

  for (int it = 0; it < nIter; ++it) {
    const int u = it * 2;
    // ---- tile u (buf0) ----
    LDA4(A0h, 0); LDB2(B0h, 0);                 // P1
    STAGE_B(1, 0, u + 1);
    BARRIER(); WAIT_LGKM0(); MFMA16(0, 0); BARRIER();
    LDA4(A0h, 1);                               // P2
    STAGE_B(1, 1, u + 1);
    BARRIER(); WAIT_LGKM0(); MFMA16(1, 0); BARRIER();
    LDB2(B0h, 1);                               // P3
    if (u + 2 < ntiles) STAGE_A(0, 0, u + 2);
    BARRIER(); WAIT_LGKM0(); MFMA16(0, 1); BARRIER();
    if (u + 2 < ntiles) STAGE_A(0, 1, u + 2);   // P4
    BARRIER(); MFMA16(1, 1);
    if (u + 2 < ntiles) { WAIT_VM4(); } else { WAIT_VM0(); }
    BARRIER();
    // ---- tile u+1 (buf1) ----
    LDA4(A1h, 0); LDB2(B1h, 0);                 // P5
    if (u + 2 < ntiles) STAGE_B(0, 0, u + 2);
    BARRIER(); WAIT_LGKM0(); MFMA16(0, 0); BARRIER();
    LDA4(A1h, 1);                               // P6
    if (u + 2 < ntiles) STAGE_B(0, 1, u + 2);
    BARRIER(); WAIT_LGKM0(); MFMA16(1, 0); BARRIER();
    LDB2(B1h, 1);                               // P7
    if (u + 3 < ntiles) STAGE_A(1, 0, u + 3);
    BARRIER(); WAIT_LGKM0(); MFMA16(0, 1); BARRIER();
    if (u + 3 < ntiles) STAGE_A(1, 1, u + 3);   // P8
    BARRIER(); MFMA16(1, 1);
    WAIT_VM4(); BARRIER();
  }

  // epilogue: C row = m0+wr*128+mi*16+lg*4+r, col = n0+wc*64+ni*16+lr
#pragma unroll
  for (int mi = 0; mi < 8; ++mi)
#pragma unroll
    for (int ni = 0; ni < 4; ++ni)
#pragma unroll
      for (int r = 0; r < 4; ++r) {
        int row = m0 + wr * 128 + mi * 16 + lg * 4 + r;
        int col = n0 + wc * 64 + ni * 16 + lr;
        size_t idx = (size_t)row * N + col;
        float v = acc[mi][ni][r];
        if (RES) v += res[idx];
        if constexpr (sizeof(OutT) == 2) C[idx] = f2bf(v);
        else                             C[idx] = v;
      }
#undef STAGE_A
#undef STAGE_B
#undef LDA4
#undef LDB2
#undef MFMA16
}

// ---------------- GEMM 256x256 8-phase, fused-SwiGLU epilogue --------------
// Separate function (NOT a new template arg on gemm256_kernel) to avoid
// perturbing the proven instantiations' codegen (rule #19 / R5 regression).
// out = silu(gate) * (A*Bt^T), bf16. gate: bf16 [M][N].
__global__ __launch_bounds__(512, 2) void gemm256_swiglu_kernel(
    const ushort* __restrict__ A, const ushort* __restrict__ Bt,
    ushort* __restrict__ C, const ushort* __restrict__ gate,
    int M, int N, int K) {
  extern __shared__ ushort lds[];
  ushort* Al = lds;
  ushort* Bl = lds + 32768;
  const int t = threadIdx.x, l = t & 63, w = t >> 6;
  const int wr = w >> 2, wc = w & 3;
  const int lr = l & 15, lg = l >> 4;
  const int rhi = lr >> 3, rlo = lr & 7;
  const int srow = l >> 3, sg = (l & 7) ^ srow;

  const int nby = M >> 8;
  const int nwg = (N >> 8) * nby;
  const int cpx = nwg >> 3;
  const int bid = (int)blockIdx.x;
  const int swz = (bid & 7) * cpx + (bid >> 3);
  const int m0 = (swz % nby) << 8;
  const int n0 = (swz / nby) << 8;

  const int lof0 = rhi * 512 + rlo * 64 + ((0 + lg) ^ rlo) * 8;
  const int lof1 = rhi * 512 + rlo * 64 + ((4 + lg) ^ rlo) * 8;

  const f32x4 fz = {0.f, 0.f, 0.f, 0.f};
  f32x4 acc[8][4];
#pragma unroll
  for (int i = 0; i < 8; ++i)
#pragma unroll
    for (int j = 0; j < 4; ++j) acc[i][j] = fz;
  bf16x8 a[8][2];
  bf16x8 bq[2][2];

  const ushort* Asrc = A + (size_t)(m0 + w * 8 + srow) * K + sg * 8;
  const ushort* Bsrc = Bt + (size_t)(n0 + w * 8 + srow) * K + sg * 8;
  const size_t rK64 = (size_t)64 * K, rK128 = (size_t)128 * K;
  ushort* Adst = Al + w * 512;
  ushort* Bdst = Bl + w * 512;

#define STAGE_A(buf, half, tile) do {                                   \
    const ushort* s_ = Asrc + (size_t)(half) * rK128 + ((tile) << 6);   \
    ushort* d_ = Adst + (buf) * 16384 + (half) * 8192;                  \
    gload16(s_, d_);                                                    \
    gload16(s_ + rK64, d_ + 4096);                                      \
  } while (0)
#define STAGE_B(buf, half, tile) do {                                   \
    const ushort* s_ = Bsrc + (size_t)(half) * rK128 + ((tile) << 6);   \
    ushort* d_ = Bdst + (buf) * 16384 + (half) * 8192;                  \
    gload16(s_, d_);                                                    \
    gload16(s_ + rK64, d_ + 4096);                                      \
  } while (0)
#define LDA4(AH, QM) do {                                                   \
    _Pragma("unroll") for (int mi_ = 0; mi_ < 4; ++mi_) {                   \
      a[(QM) * 4 + mi_][0] =                                                \
          *(const bf16x8*)((AH) + ((QM) * 4 + mi_) * 1024 + lof0);          \
      a[(QM) * 4 + mi_][1] =                                                \
          *(const bf16x8*)((AH) + ((QM) * 4 + mi_) * 1024 + lof1);          \
    } } while (0)
#define LDB2(BH, NQ) do {                                                   \
    _Pragma("unroll") for (int nj_ = 0; nj_ < 2; ++nj_) {                   \
      bq[nj_][0] = *(const bf16x8*)((BH) + ((NQ) * 2 + nj_) * 1024 + lof0); \
      bq[nj_][1] = *(const bf16x8*)((BH) + ((NQ) * 2 + nj_) * 1024 + lof1); \
    } } while (0)
#define MFMA16(QM, QN)                                                      \
    __builtin_amdgcn_s_setprio(1);                                          \
    _Pragma("unroll") for (int mi_ = 0; mi_ < 4; ++mi_)                     \
    _Pragma("unroll") for (int nj_ = 0; nj_ < 2; ++nj_) {                   \
      acc[(QM) * 4 + mi_][(QN) * 2 + nj_] =                                 \
          __builtin_amdgcn_mfma_f32_16x16x32_bf16(                          \
              a[(QM) * 4 + mi_][0], bq[nj_][0],                             \
              acc[(QM) * 4 + mi_][(QN) * 2 + nj_], 0, 0, 0);                \
      acc[(QM) * 4 + mi_][(QN) * 2 + nj_] =                                 \
          __builtin_amdgcn_mfma_f32_16x16x32_bf16(                          \
              a[(QM) * 4 + mi_][1], bq[nj_][1],                             \
              acc[(QM) * 4 + mi_][(QN) * 2 + nj_], 0, 0, 0);                \
    }                                                                       \
    __builtin_amdgcn_s_setprio(0);

  const ushort* A0h = Al + wr * 8192;
  const ushort* A1h = A0h + 16384;
  const ushort* B0h = Bl + (wc >> 1) * 8192 + (wc & 1) * 4096;
  const ushort* B1h = B0h + 16384;

  const int ntiles = K >> 6, nIter = K >> 7;
  STAGE_A(0, 0, 0); STAGE_A(0, 1, 0); STAGE_B(0, 0, 0); STAGE_B(0, 1, 0);
  STAGE_A(1, 0, 1); STAGE_A(1, 1, 1);
  WAIT_VM4(); BARRIER();

  for (int it = 0; it < nIter; ++it) {
    const int u = it * 2;
    LDA4(A0h, 0); LDB2(B0h, 0);
    STAGE_B(1, 0, u + 1);
    BARRIER(); WAIT_LGKM0(); MFMA16(0, 0); BARRIER();
    LDA4(A0h, 1);
    STAGE_B(1, 1, u + 1);
    BARRIER(); WAIT_LGKM0(); MFMA16(1, 0); BARRIER();
    LDB2(B0h, 1);
    if (u + 2 < ntiles) STAGE_A(0, 0, u + 2);
    BARRIER(); WAIT_LGKM0(); MFMA16(0, 1); BARRIER();
    if (u + 2 < ntiles) STAGE_A(0, 1, u + 2);
    BARRIER(); MFMA16(1, 1);
    if (u + 2 < ntiles) { WAIT_VM4(); } else { WAIT_VM0(); }
    BARRIER();
    LDA4(A1h, 0); LDB2(B1h, 0);
    if (u + 2 < ntiles) STAGE_B(0, 0, u + 2);
    BARRIER(); WAIT_LGKM0(); MFMA16(0, 0); BARRIER();
    LDA4(A1h, 1);
    if (u + 2 < ntiles) STAGE_B(0, 1, u + 2);
    BARRIER(); WAIT_LGKM0(); MFMA16(1, 0); BARRIER();
    LDB2(B1h, 1);
    if (u + 3 < ntiles) STAGE_A(1, 0, u + 3);
    BARRIER(); WAIT_LGKM0(); MFMA16(0, 1); BARRIER();
    if (u + 3 < ntiles) STAGE_A(1, 1, u + 3);
    BARRIER(); MFMA16(1, 1);
    WAIT_VM4(); BARRIER();
  }

  // fused epilogue: out = silu(gate) * acc
#pragma unroll
  for (int mi = 0; mi < 8; ++mi)
#pragma unroll
    for (int ni = 0; ni < 4; ++ni)
#pragma unroll
      for (int r = 0; r < 4; ++r) {
        int row = m0 + wr * 128 + mi * 16 + lg * 4 + r;
        int col = n0 + wc * 64 + ni * 16 + lr;
        size_t idx = (size_t)row * N + col;
        float g = bf2f(gate[idx]);
        float s = g / (1.f + __expf(-g));
        C[idx] = f2bf(s * acc[mi][ni][r]);
      }
#undef STAGE_A
#undef STAGE_B
#undef LDA4
#undef LDB2
#undef MFMA16
}

// ------------------------------ RoPE table ---------------------------------
__global__ void rope_table_kernel(const int* __restrict__ pos,
                                  float2* __restrict__ tab) {
  int idx = blockIdx.x * 256 + threadIdx.x;  // 2048*64
  int s = idx >> 6, fi = idx & 63;
  float inv = (float)exp(-(double)(2 * fi) / 128.0 * 9.210340371976184);
  float a = (float)pos[s] * inv;
  tab[idx] = make_float2(cosf(a), sinf(a));
}

// --------- RoPE + scatter qkv[T,6144] -> Qr[b,h,s,d] Kr[b,h,s,d] Vt[b,h,d,s]
__global__ __launch_bounds__(256) void rope_scatter_kernel(
    const ushort* __restrict__ qkv, const float2* __restrict__ tab,
    ushort* __restrict__ Qr, ushort* __restrict__ Kr, ushort* __restrict__ Vt) {
  __shared__ ushort vt[64][132];
  const int t = threadIdx.x, tt = blockIdx.x, h = blockIdx.y;  // h: 0..47
  const int row = t >> 2, c = (t & 3) * 16;
  const int tok = tt * 64 + row;
  const int b = tok >> 11, s = tok & 2047;
  const ushort* ip = qkv + (size_t)tok * 6144 + h * 128;
  union U { uint4 v; ushort us[8]; };
  U a0, a1, b0, b1;
  a0.v = *(const uint4*)(ip + c);      a1.v = *(const uint4*)(ip + c + 8);
  b0.v = *(const uint4*)(ip + c + 64); b1.v = *(const uint4*)(ip + c + 72);
  if (h < 40) {  // q or k head: NeoX rope on pairs (i, i+64)
    U o0, o1, o2, o3;
#pragma unroll
    for (int j = 0; j < 8; ++j) {
      float2 cs = tab[s * 64 + c + j];
      float x1 = bf2f(a0.us[j]), x2 = bf2f(b0.us[j]);
      o0.us[j] = f2bf(x1 * cs.x - x2 * cs.y);
      o2.us[j] = f2bf(x2 * cs.x + x1 * cs.y);
    }
#pragma unroll
    for (int j = 0; j < 8; ++j) {
      float2 cs = tab[s * 64 + c + 8 + j];
      float x1 = bf2f(a1.us[j]), x2 = bf2f(b1.us[j]);
      o1.us[j] = f2bf(x1 * cs.x - x2 * cs.y);
      o3.us[j] = f2bf(x2 * cs.x + x1 * cs.y);
    }
    ushort* base;
    if (h < 32) base = Qr + ((size_t)((b * 32 + h) * 2048 + s)) * 128;
    else        base = Kr + ((size_t)((b * 8 + (h - 32)) * 2048 + s)) * 128;
    *(uint4*)(base + c)      = o0.v; *(uint4*)(base + c + 8)  = o1.v;
    *(uint4*)(base + c + 64) = o2.v; *(uint4*)(base + c + 72) = o3.v;
  } else {  // v head: LDS transpose -> Vt[b,hv,d,s]
    const int hv = h - 40;
#pragma unroll
    for (int j = 0; j < 8; ++j) {
      vt[row][c + j]      = a0.us[j]; vt[row][c + 8 + j]  = a1.us[j];
      vt[row][c + 64 + j] = b0.us[j]; vt[row][c + 72 + j] = b1.us[j];
    }
    __syncthreads();
    const int d = t >> 1, s0 = (t & 1) * 32, sb = (tt & 31) * 64;
    U w0, w1, w2, w3;
#pragma unroll
    for (int j = 0; j < 8; ++j) {
      w0.us[j] = vt[s0 + j][d];      w1.us[j] = vt[s0 + 8 + j][d];
      w2.us[j] = vt[s0 + 16 + j][d]; w3.us[j] = vt[s0 + 24 + j][d];
    }
    ushort* vb = Vt + ((size_t)((b * 8 + hv) * 128 + d)) * 2048 + sb + s0;
    *(uint4*)(vb) = w0.v;      *(uint4*)(vb + 8) = w1.v;
    *(uint4*)(vb + 16) = w2.v; *(uint4*)(vb + 24) = w3.v;
  }
}

// --------------------------- flash attention -------------------------------
// QBLK=128, 8 waves, KVBLK=64; XOR-swizzled K/V/P LDS, K/V dbuf vmcnt(4),
// log2 softmax, MFMA row-sum, defer-max THR=8, wave-uniform mask.
__global__ __launch_bounds__(512) void attn_kernel(
    const ushort* __restrict__ Q, const ushort* __restrict__ K,
    const ushort* __restrict__ V, ushort* __restrict__ O) {
  extern __shared__ ushort sm[];
  ushort* Kl = sm;           // [2][64 s][128 d]
  ushort* Vl = sm + 16384;   // [2][128 d][64 s]
  ushort* Pl = sm + 32768;   // [128][64]
  const int t = threadIdx.x, l = t & 63, w = t >> 6;   // w: 0..7
  const int lr = l & 15, lg = l >> 4;
  const int qb = blockIdx.x, h = blockIdx.y, b = blockIdx.z;
  const int hkv = h >> 2;
  const f32x4 fzero = {0.f, 0.f, 0.f, 0.f};

  const int rm = lr & 7;
  int ksw[4], vsw[2];
#pragma unroll
  for (int ks = 0; ks < 4; ++ks) ksw[ks] = ((ks * 4 + lg) ^ rm) * 8;
  vsw[0] = (lg ^ rm) * 8;
  vsw[1] = ((4 + lg) ^ rm) * 8;
  const int kcol = ((t & 15) ^ ((t >> 4) & 7)) * 8;   // staging src swizzle
  const int vcol = ((t & 7) ^ ((t >> 3) & 7)) * 8;

  const float qscale = 0.08838834764831845f * 1.4426950408889634f;
  const ushort* qp =
      Q + ((size_t)((b * 32 + h) * 2048 + qb * 128 + w * 16 + lr)) * 128 + lg * 8;
  bf16x8 qf[4];
#pragma unroll
  for (int ks = 0; ks < 4; ++ks) {
    bf16x8 raw = *(const bf16x8*)(qp + ks * 32);
#pragma unroll
    for (int j = 0; j < 8; ++j)
      qf[ks][j] = (short)f2bf(bf2f((ushort)raw[j]) * qscale);
  }
  bf16x8 ones;
#pragma unroll
  for (int j = 0; j < 8; ++j) ones[j] = (short)0x3F80;
  WAIT_VM0();

  const ushort* kg = K + ((size_t)(b * 8 + hkv)) * 2048 * 128;
  const ushort* vg = V + ((size_t)(b * 8 + hkv)) * 128 * 2048;

#define STAGE_KV(buf, s0_) do {                                              \
    _Pragma("unroll") for (int i_ = 0; i_ < 2; ++i_)                         \
      gload16(kg + (size_t)((s0_) + i_ * 32 + (t >> 4)) * 128 + kcol,        \
              (char*)Kl + (buf) * 16384 + i_ * 8192 + t * 16);               \
    _Pragma("unroll") for (int i_ = 0; i_ < 2; ++i_)                         \
      gload16(vg + (size_t)(i_ * 64 + (t >> 3)) * 2048 + (s0_) + vcol,       \
              (char*)Vl + (buf) * 16384 + i_ * 8192 + t * 16);               \
  } while (0)

  f32x4 accO[8];
#pragma unroll
  for (int i = 0; i < 8; ++i) accO[i] = fzero;
  float m_r[4] = {-1e30f, -1e30f, -1e30f, -1e30f};
  float l_r[4] = {0.f, 0.f, 0.f, 0.f};
  const int qrow = qb * 128 + w * 16 + lg * 4;
  const int wrow0 = qb * 128 + w * 16;
  const int jend = 2 * qb + 1;

  STAGE_KV(0, 0);
  for (int j = 0; j <= jend; ++j) {
    if (j < jend) { STAGE_KV((j + 1) & 1, (j + 1) * 64); WAIT_VM4(); }
    else          { WAIT_VM0(); }
    BARRIER();
    const ushort* Kb = Kl + (j & 1) * 8192;
    const ushort* Vb = Vl + (j & 1) * 8192;

    f32x4 sc[4];
#pragma unroll
    for (int ni = 0; ni < 4; ++ni) sc[ni] = fzero;
    __builtin_amdgcn_s_setprio(1);
#pragma unroll
    for (int ni = 0; ni < 4; ++ni)
#pragma unroll
      for (int ks = 0; ks < 4; ++ks) {
        bf16x8 kf = *(const bf16x8*)(Kb + (ni * 16 + lr) * 128 + ksw[ks]);
        sc[ni] = __builtin_amdgcn_mfma_f32_16x16x32_bf16(qf[ks], kf, sc[ni], 0, 0, 0);
      }
    __builtin_amdgcn_s_setprio(0);
    if (j * 64 + 63 > wrow0) {
#pragma unroll
      for (int ni = 0; ni < 4; ++ni)
#pragma unroll
        for (int r = 0; r < 4; ++r)
          if (j * 64 + ni * 16 + lr > qrow + r) sc[ni][r] = -1e30f;
    }
    float mx[4];
#pragma unroll
    for (int r = 0; r < 4; ++r) {
      float v = fmaxf(fmaxf(sc[0][r], sc[1][r]), fmaxf(sc[2][r], sc[3][r]));
#pragma unroll
      for (int m = 8; m; m >>= 1) v = fmaxf(v, __shfl_xor(v, m));
      mx[r] = v;
    }
    bool ok = mx[0] <= m_r[0] + 8.f && mx[1] <= m_r[1] + 8.f &&
              mx[2] <= m_r[2] + 8.f && mx[3] <= m_r[3] + 8.f;
    if (!__all(ok)) {
#pragma unroll
      for (int r = 0; r < 4; ++r) {
        float mnew = fmaxf(m_r[r], mx[r]);
        float fsc = exp2f(m_r[r] - mnew);
        l_r[r] *= fsc;
        m_r[r] = mnew;
#pragma unroll
        for (int i = 0; i < 8; ++i) accO[i][r] *= fsc;
      }
    }
#pragma unroll
    for (int ni = 0; ni < 4; ++ni)
#pragma unroll
      for (int r = 0; r < 4; ++r) {
        int prow = w * 16 + lg * 4 + r;
        int slot = (ni * 2 + (lr >> 3)) ^ (prow & 7);
        Pl[prow * 64 + slot * 8 + rm] = f2bf(exp2f(sc[ni][r] - m_r[r]));
      }
    WAIT_LGKM0();
    f32x4 accL = fzero;
    __builtin_amdgcn_s_setprio(1);
#pragma unroll
    for (int ks = 0; ks < 2; ++ks) {
      bf16x8 pf = *(const bf16x8*)(Pl + (w * 16 + lr) * 64 + vsw[ks]);
#pragma unroll
      for (int nf = 0; nf < 8; ++nf) {
        bf16x8 vf = *(const bf16x8*)(Vb + (nf * 16 + lr) * 64 + vsw[ks]);
        accO[nf] = __builtin_amdgcn_mfma_f32_16x16x32_bf16(pf, vf, accO[nf], 0, 0, 0);
      }
      accL = __builtin_amdgcn_mfma_f32_16x16x32_bf16(pf, ones, accL, 0, 0, 0);
    }
    __builtin_amdgcn_s_setprio(0);
#pragma unroll
    for (int r = 0; r < 4; ++r) l_r[r] += accL[r];
    BARRIER();
  }
#undef STAGE_KV
  float invl[4];
#pragma unroll
  for (int r = 0; r < 4; ++r) invl[r] = 1.f / l_r[r];
#pragma unroll
  for (int nf = 0; nf < 8; ++nf)
#pragma unroll
    for (int r = 0; r < 4; ++r) {
      int q = qb * 128 + w * 16 + lg * 4 + r;
      int d = nf * 16 + lr;
      O[((size_t)(b * 2048 + q)) * 4096 + h * 128 + d] = f2bf(accO[nf][r] * invl[r]);
    }
}

// ------------------------------ launcher -----------------------------------
#define OFF_W    ((size_t)0)
#define OFF_H1   ((size_t)90177536)
#define OFF_XN   ((size_t)157286400)
#define OFF_QKV  ((size_t)190840832)
#define OFF_TAB  ((size_t)241172480)
#define OFF_QR   ((size_t)242221056)
#define OFF_KR   ((size_t)275775488)
#define OFF_VT   ((size_t)284164096)
#define OFF_ATTN ((size_t)292552704)
#define OFF_GATE OFF_QKV
#define OFF_UP   ((size_t)326107136)
#define WS_NEED  ((size_t)416284672)

extern "C" void kernel_launch(void* const* d_in, const int* in_sizes, int n_in,
                              void* d_out, int out_size, void* d_ws,
                              size_t ws_size, hipStream_t stream) {
  (void)in_sizes; (void)n_in; (void)out_size;
  if (ws_size < WS_NEED) return;
  const float* hs     = (const float*)d_in[0];
  const int*   pos    = (const int*)d_in[1];
  const float* w_qkv  = (const float*)d_in[2];
  const float* w_o    = (const float*)d_in[3];
  const float* w_gu   = (const float*)d_in[4];
  const float* w_down = (const float*)d_in[5];
  const float* ln1    = (const float*)d_in[6];
  const float* ln2    = (const float*)d_in[7];
  float* out = (float*)d_out;
  char* ws = (char*)d_ws;

  ushort* W    = (ushort*)(ws + OFF_W);
  float*  h1   = (float*)(ws + OFF_H1);
  ushort* xn   = (ushort*)(ws + OFF_XN);
  ushort* qkv  = (ushort*)(ws + OFF_QKV);
  float2* tab  = (float2*)(ws + OFF_TAB);
  ushort* Qr   = (ushort*)(ws + OFF_QR);
  ushort* Kr   = (ushort*)(ws + OFF_KR);
  ushort* Vt   = (ushort*)(ws + OFF_VT);
  ushort* attn = (ushort*)(ws + OFF_ATTN);
  ushort* gate = (ushort*)(ws + OFF_GATE);
  ushort* act  = (ushort*)(ws + OFF_UP);

  auto kb = gemm256_kernel<ushort, false>;
  auto kf = gemm256_kernel<float, true>;
  hipFuncSetAttribute((const void*)kb, hipFuncAttributeMaxDynamicSharedMemorySize, 131072);
  hipFuncSetAttribute((const void*)kf, hipFuncAttributeMaxDynamicSharedMemorySize, 131072);
  hipFuncSetAttribute((const void*)gemm256_swiglu_kernel, hipFuncAttributeMaxDynamicSharedMemorySize, 131072);
  hipFuncSetAttribute((const void*)attn_kernel, hipFuncAttributeMaxDynamicSharedMemorySize, 81920);

  // --- attention block ---
  rmsnorm_kernel<<<4096, 256, 0, stream>>>(hs, ln1, xn);
  transpose_cast_kernel<<<dim3(64, 96), 256, 0, stream>>>(w_qkv, W, 6144, 0, 4096);
  gemm256_kernel<ushort, false><<<384, 512, 131072, stream>>>(
      xn, W, qkv, nullptr, 4096, 6144, 4096);
  rope_table_kernel<<<512, 256, 0, stream>>>(pos, tab);
  rope_scatter_kernel<<<dim3(64, 48), 256, 0, stream>>>(qkv, tab, Qr, Kr, Vt);
  attn_kernel<<<dim3(16, 32, 2), 512, 81920, stream>>>(Qr, Kr, Vt, attn);
  transpose_cast_kernel<<<dim3(64, 64), 256, 0, stream>>>(w_o, W, 4096, 0, 4096);
  gemm256_kernel<float, true><<<256, 512, 131072, stream>>>(
      attn, W, h1, hs, 4096, 4096, 4096);

  // --- MLP block ---
  rmsnorm_kernel<<<4096, 256, 0, stream>>>(h1, ln2, xn);
  transpose_cast_kernel<<<dim3(64, 172), 256, 0, stream>>>(w_gu, W, 22016, 0, 4096);
  gemm256_kernel<ushort, false><<<688, 512, 131072, stream>>>(
      xn, W, gate, nullptr, 4096, 11008, 4096);
  transpose_cast_kernel<<<dim3(64, 172), 256, 0, stream>>>(w_gu, W, 22016, 11008, 4096);
  gemm256_swiglu_kernel<<<688, 512, 131072, stream>>>(
      xn, W, act, gate, 4096, 11008, 4096);
  transpose_cast_kernel<<<dim3(172, 64), 256, 0, stream>>>(w_down, W, 4096, 0, 11008);
  gemm256_kernel<float, true><<<256, 512, 131072, stream>>>(
      act, W, out, h1, 4096, 4096, 11008);
}